// Round 4
// baseline (1072.574 us; speedup 1.0000x reference)
//
#include <hip/hip_runtime.h>

#define HW (128*128)

typedef __bf16 bf16x8 __attribute__((ext_vector_type(8)));
typedef float  float4v __attribute__((ext_vector_type(4)));
typedef int    int4v   __attribute__((ext_vector_type(4)));
typedef int    int2v   __attribute__((ext_vector_type(2)));

static __device__ __forceinline__ short f2bf(float f) {
    unsigned u = __float_as_uint(f);
    unsigned r = (u + 0x7FFFu + ((u >> 16) & 1u)) >> 16;
    return (short)(r & 0xFFFFu);
}
static __device__ __forceinline__ int pack2(short a, short b) {
    return (int)((unsigned short)a | ((unsigned)(unsigned short)b << 16));
}
// async global->LDS, 16B per lane; LDS dest = wave-uniform base + lane*16
static __device__ __forceinline__ void async_cp16(const void* g, void* l) {
    __builtin_amdgcn_global_load_lds(
        (const __attribute__((address_space(1))) unsigned int*)g,
        (__attribute__((address_space(3))) unsigned int*)l, 16, 0, 0);
}

// ---------------------------------------------------------------------------
// prep: pre-swizzled bf16 weight streams (LDS-chunk order per K-step), zero
// buffer, h2p halo zeroing.
// Swizzle rule (64B rows, 4 chunks): LDS chunk (n,c) holds k-chunk c^((n>>1)&3).
// ---------------------------------------------------------------------------
__global__ __launch_bounds__(256) void prep_weights(
    const float* __restrict__ W1, const float* __restrict__ W2,
    const float* __restrict__ W3,
    short* __restrict__ W1sw, short* __restrict__ W2sw, short* __restrict__ W3sw,
    char* __restrict__ h2p, int4v* __restrict__ zerobuf)
{
    int tid = blockIdx.x * 256 + threadIdx.x;
    int stride = gridDim.x * 256;
    // W1sw: 5 steps x 256 chunks x 8 elems (k-chunk gc -> tap=2s+(gc>>1), ch0=(gc&1)*8)
    for (int i = tid; i < 5*256*8; i += stride) {
        int e = i & 7, q = (i >> 3) & 255, s = i >> 11;
        int n = q >> 2, c = q & 3;
        int gc = c ^ ((n >> 1) & 3);
        int tap = 2*s + (gc >> 1);
        int ch = (gc & 1)*8 + e;
        float v = 0.f;
        if (tap < 9) {
            int ky = (tap*11) >> 5; int kx = tap - 3*ky;
            v = W1[((n*16 + ch)*3 + ky)*3 + kx];
        }
        W1sw[i] = f2bf(v);
    }
    // W2sw: 2 x 256 x 8 (k = s*32 + gc*8 + e)
    for (int i = tid; i < 2*256*8; i += stride) {
        int e = i & 7, q = (i >> 3) & 255, s = i >> 11;
        int n = q >> 2, c = q & 3;
        int gc = c ^ ((n >> 1) & 3);
        int k = s*32 + gc*8 + e;
        W2sw[i] = f2bf(W2[n*64 + k]);
    }
    // W3sw: 18 x 1152 x 8 ; n = ch*24+j (j==23 pad), k = s*32+gc*8+e -> tap=k>>6, ci=k&63
    for (int i = tid; i < 18*1152*8; i += stride) {
        int e = i & 7;
        int q = (i >> 3) % 1152;
        int s = i / (1152*8);
        int n = q >> 2, c = q & 3;
        int gc = c ^ ((n >> 1) & 3);
        int k = s*32 + gc*8 + e;
        int tap = k >> 6, ci = k & 63;
        int ch = n / 24, j = n - 24*ch;
        float v = 0.f;
        if (j < 23) v = W3[((ch*23 + j)*64 + ci)*9 + tap];
        W3sw[i] = f2bf(v);
    }
    for (int i = tid; i < 64; i += stride) { int4v zz = {0,0,0,0}; zerobuf[i] = zz; }
    // h2p halo zero: 16 batches x 516 border px x 8 chunks
    for (int i = tid; i < 16*516*8; i += stride) {
        int cchunk = i & 7, pxi = (i >> 3) % 516, b = i / (516*8);
        int yy, xx;
        if (pxi < 130)      { yy = 0;   xx = pxi; }
        else if (pxi < 260) { yy = 129; xx = pxi - 130; }
        else if (pxi < 388) { yy = pxi - 260 + 1; xx = 0; }
        else                { yy = pxi - 388 + 1; xx = 129; }
        int4v zz = {0,0,0,0};
        *(int4v*)(h2p + (size_t)((b*130 + yy)*130 + xx)*128 + cchunk*16) = zz;
    }
}

// ---------------------------------------------------------------------------
// pack z with 1-px halo: (16,130,130,16ch) bf16; interior ch0-11 = masked x,
// ch12-15 = cond; halo rows/cols zero. Also init logdet outputs.
// ---------------------------------------------------------------------------
__global__ __launch_bounds__(256) void pack_z(
    const float* __restrict__ x, const float* __restrict__ cond,
    const float* __restrict__ logdet_in,
    short* __restrict__ zp, float* __restrict__ logdet_out)
{
    int id = blockIdx.x * 256 + threadIdx.x;
    if (id < 16) logdet_out[id] = logdet_in[id];
    if (id >= 16*130*130) return;
    int b = id / 16900;
    int rem = id - b*16900;
    int yy = rem / 130;
    int xx = rem - yy*130;
    short vs[16];
    #pragma unroll
    for (int c = 0; c < 16; ++c) vs[c] = 0;
    if (yy >= 1 && yy <= 128 && xx >= 1 && xx <= 128) {
        int pix = (yy - 1)*128 + (xx - 1);
        bool frozen = ((yy + xx) & 1) == 1;
        #pragma unroll
        for (int c = 0; c < 12; ++c)
            vs[c] = f2bf(frozen ? x[(b*12 + c)*HW + pix] : 0.f);
        #pragma unroll
        for (int c = 0; c < 4; ++c)
            vs[12 + c] = f2bf(cond[(b*4 + c)*HW + pix]);
    }
    int4v lo = { pack2(vs[0],vs[1]),  pack2(vs[2],vs[3]),
                 pack2(vs[4],vs[5]),  pack2(vs[6],vs[7]) };
    int4v hi = { pack2(vs[8],vs[9]),  pack2(vs[10],vs[11]),
                 pack2(vs[12],vs[13]),pack2(vs[14],vs[15]) };
    *(int4v*)(zp + id*16)     = lo;
    *(int4v*)(zp + id*16 + 8) = hi;
}

// ---------------------------------------------------------------------------
// fused conv1 (3x3, 16->64) + conv2 (1x1, 64->64). Block = one image row.
// Operands swapped: A = weights (M=out-ch), B = pixels (N=px) so D cols = px.
// LDS: z-tile [128px][32k] (8K) | W [64][32k] (4K) | h1/h2 tile [128px][64ch] (16K)
// ---------------------------------------------------------------------------
__global__ __launch_bounds__(256, 4) void conv12_kernel(
    const char* __restrict__ zp, const char* __restrict__ W1sw,
    const char* __restrict__ W2sw,
    const float* __restrict__ b1, const float* __restrict__ b2,
    const char* __restrict__ zerobuf, char* __restrict__ h2p)
{
    __shared__ __align__(16) char smem[28672];
    int t = threadIdx.x;
    int lane = t & 63, w = t >> 6;
    int l15 = lane & 15, quad = lane >> 4;
    int bid = blockIdx.x;
    int b = bid >> 7, y = bid & 127;
    int chb = (w >> 1) * 32;
    int pxb = (w & 1) * 64;
    unsigned wbase = (unsigned)__builtin_amdgcn_readfirstlane(w << 10);

    // staging constants: chunk q -> px=q>>2, c=q&3, gc=c^((px>>1)&3)
    int px1 = t >> 2;
    int gc1 = (t & 3) ^ ((px1 >> 1) & 3);
    int tl1 = gc1 >> 1, zoff1 = px1*32 + (gc1 & 1)*16;
    int q2 = t + 256;
    int px2 = q2 >> 2;
    int gc2 = (q2 & 3) ^ ((px2 >> 1) & 3);
    int tl2 = gc2 >> 1, zoff2 = px2*32 + (gc2 & 1)*16;

    int waddr[2], zaddr[4];
    #pragma unroll
    for (int i = 0; i < 2; ++i) {
        int n = chb + i*16 + l15;
        waddr[i] = 8192 + n*64 + ((quad ^ ((n >> 1) & 3)) << 4);
    }
    #pragma unroll
    for (int j = 0; j < 4; ++j) {
        int px = pxb + j*16 + l15;
        zaddr[j] = px*64 + ((quad ^ ((px >> 1) & 3)) << 4);
    }

    const char* zb = zp + (size_t)(b*16900)*32;
    const float4v z4 = {0.f,0.f,0.f,0.f};
    float4v acc[2][4];
    #pragma unroll
    for (int i = 0; i < 2; ++i)
        #pragma unroll
        for (int j = 0; j < 4; ++j) acc[i][j] = z4;

    // ---- conv1: 5 K-steps of 32 (taps 2s, 2s+1; tap 9 = zero pad) ----
    for (int s = 0; s < 5; ++s) {
        __syncthreads();
        int ta = 2*s + tl1;
        const char* g1;
        if (ta < 9) { int ky = (ta*11) >> 5; int kx = ta - 3*ky;
            g1 = zb + ((y + ky)*130 + kx)*32 + zoff1; }
        else g1 = zerobuf + (lane << 4);
        async_cp16(g1, smem + wbase);
        int tb = 2*s + tl2;
        const char* g2;
        if (tb < 9) { int ky = (tb*11) >> 5; int kx = tb - 3*ky;
            g2 = zb + ((y + ky)*130 + kx)*32 + zoff2; }
        else g2 = zerobuf + (lane << 4);
        async_cp16(g2, smem + 4096 + wbase);
        async_cp16(W1sw + s*4096 + (t << 4), smem + 8192 + wbase);
        __syncthreads();
        bf16x8 aw[2];
        #pragma unroll
        for (int i = 0; i < 2; ++i) aw[i] = *(const bf16x8*)(smem + waddr[i]);
        #pragma unroll
        for (int j = 0; j < 4; ++j) {
            bf16x8 bzv = *(const bf16x8*)(smem + zaddr[j]);
            #pragma unroll
            for (int i = 0; i < 2; ++i)
                acc[i][j] = __builtin_amdgcn_mfma_f32_16x16x32_bf16(aw[i], bzv, acc[i][j], 0, 0, 0);
        }
    }
    // ---- conv1 epilogue: bias+ReLU+bf16 -> h1 tile [px][64ch], 8-chunk XOR swizzle ----
    {
        #pragma unroll
        for (int i = 0; i < 2; ++i) {
            int ch0 = chb + i*16 + quad*4;
            float bb0 = b1[ch0], bb1 = b1[ch0+1], bb2 = b1[ch0+2], bb3 = b1[ch0+3];
            #pragma unroll
            for (int j = 0; j < 4; ++j) {
                int px = pxb + j*16 + l15;
                short s0 = f2bf(fmaxf(acc[i][j][0] + bb0, 0.f));
                short s1 = f2bf(fmaxf(acc[i][j][1] + bb1, 0.f));
                short s2 = f2bf(fmaxf(acc[i][j][2] + bb2, 0.f));
                short s3 = f2bf(fmaxf(acc[i][j][3] + bb3, 0.f));
                int2v pk = { pack2(s0, s1), pack2(s2, s3) };
                *(int2v*)(smem + 12288 + px*128 + (((ch0 >> 3) ^ (px & 7)) << 4) + ((ch0 & 7) << 1)) = pk;
            }
        }
    }
    // ---- conv2: 2 K-steps of 32 ----
    float4v acc2[2][4];
    #pragma unroll
    for (int i = 0; i < 2; ++i)
        #pragma unroll
        for (int j = 0; j < 4; ++j) acc2[i][j] = z4;
    for (int s = 0; s < 2; ++s) {
        __syncthreads();
        async_cp16(W2sw + s*4096 + (t << 4), smem + 8192 + wbase);
        __syncthreads();
        bf16x8 aw[2];
        #pragma unroll
        for (int i = 0; i < 2; ++i) aw[i] = *(const bf16x8*)(smem + waddr[i]);
        #pragma unroll
        for (int j = 0; j < 4; ++j) {
            int px = pxb + j*16 + l15;
            bf16x8 bh = *(const bf16x8*)(smem + 12288 + px*128 + (((s*4 + quad) ^ (px & 7)) << 4));
            #pragma unroll
            for (int i = 0; i < 2; ++i)
                acc2[i][j] = __builtin_amdgcn_mfma_f32_16x16x32_bf16(aw[i], bh, acc2[i][j], 0, 0, 0);
        }
    }
    __syncthreads();   // all h1 reads done; reuse tile region for h2
    {
        #pragma unroll
        for (int i = 0; i < 2; ++i) {
            int ch0 = chb + i*16 + quad*4;
            float bb0 = b2[ch0], bb1 = b2[ch0+1], bb2 = b2[ch0+2], bb3 = b2[ch0+3];
            #pragma unroll
            for (int j = 0; j < 4; ++j) {
                int px = pxb + j*16 + l15;
                short s0 = f2bf(fmaxf(acc2[i][j][0] + bb0, 0.f));
                short s1 = f2bf(fmaxf(acc2[i][j][1] + bb1, 0.f));
                short s2 = f2bf(fmaxf(acc2[i][j][2] + bb2, 0.f));
                short s3 = f2bf(fmaxf(acc2[i][j][3] + bb3, 0.f));
                int2v pk = { pack2(s0, s1), pack2(s2, s3) };
                *(int2v*)(smem + 12288 + px*128 + (((ch0 >> 3) ^ (px & 7)) << 4) + ((ch0 & 7) << 1)) = pk;
            }
        }
    }
    __syncthreads();
    // copy h2 tile to global (unswizzle on LDS read; coalesced global store)
    char* dst = h2p + ((size_t)(b*130 + y + 1)*130 + 1)*128;
    #pragma unroll
    for (int u = 0; u < 4; ++u) {
        int q = t + u*256;
        int px = q >> 3, g = q & 7;
        int4v v = *(const int4v*)(smem + 12288 + px*128 + ((g ^ (px & 7)) << 4));
        *(int4v*)(dst + px*128 + (g << 4)) = v;
    }
}

// ---------------------------------------------------------------------------
// conv3 (3x3, 64 -> 276 pad 288) fused with RQS + logdet.
// Block = one row, 768 threads = 12 waves: (px-half 2) x (col-group-of-48 6).
// Wave acc = 4x3 float4 = 48 regs -> no spill at 3 waves/SIMD.
// A = pixels (M), B = weights (N). 18 K-steps of 32. RQS at ALL pixels.
// ---------------------------------------------------------------------------
__global__ __launch_bounds__(768, 3) void conv3_rqs_kernel(
    const char* __restrict__ h2p, const char* __restrict__ W3sw,
    const float* __restrict__ b3, const float* __restrict__ x,
    float* __restrict__ out, float* __restrict__ logdet_out)
{
    __shared__ __align__(16) char smem[80976];
    // staging: [0,8192) A-tile (128px x 64B) | [8192,26624) B-tile (1152 chunks)
    // epilogue: [0,79872) = 12 waves x 32rows x 52 floats | [79872,80976) b3
    int t = threadIdx.x;
    int lane = t & 63, w = t >> 6;
    int l15 = lane & 15, quad = lane >> 4;
    int bid = blockIdx.x;
    int b = bid >> 7, y = bid & 127;

    float* b3s = (float*)(smem + 79872);
    if (t < 276) b3s[t] = b3[t];

    int p = w >> 1;            // wait: assign p = w&1? use p = w/6
    int colg;
    p = (w >= 6) ? 1 : 0;
    colg = w - 6*p;            // 0..5
    int pxb = p << 6;          // 0 or 64
    int cb = colg * 48;

    int aaddr[4], baddr[3];
    #pragma unroll
    for (int i = 0; i < 4; ++i) {
        int row = pxb + i*16 + l15;
        aaddr[i] = row*64 + ((quad ^ ((row >> 1) & 3)) << 4);
    }
    #pragma unroll
    for (int j = 0; j < 3; ++j) {
        int n = cb + j*16 + l15;
        baddr[j] = 8192 + n*64 + ((quad ^ ((n >> 1) & 3)) << 4);
    }

    // A staging (waves 0..7): chunk t -> px = t>>2, gc = (t&3)^((px>>1)&3)
    int pxs = t >> 2;
    int gcs = (t & 3) ^ ((pxs >> 1) & 3);
    int offA = pxs*128 + gcs*16;
    unsigned wbase = (unsigned)__builtin_amdgcn_readfirstlane(w << 10);

    const float4v z4 = {0.f,0.f,0.f,0.f};
    float4v acc[4][3];
    #pragma unroll
    for (int i = 0; i < 4; ++i)
        #pragma unroll
        for (int j = 0; j < 3; ++j) acc[i][j] = z4;

    const char* h2pb = h2p + (size_t)(b*130)*130*128;
    for (int s = 0; s < 18; ++s) {
        int tap = s >> 1, kh = s & 1;
        int td3 = (tap*11) >> 5;
        int tm3 = tap - 3*td3;
        const char* sbA = h2pb + ((y + td3)*130 + tm3)*128 + kh*64;
        const char* sbB = W3sw + s*18432;
        __syncthreads();
        if (w < 8)  async_cp16(sbA + offA, smem + wbase);
        async_cp16(sbB + (t << 4), smem + 8192 + wbase);
        if (w < 6)  async_cp16(sbB + 12288 + (t << 4), smem + 20480 + wbase);
        __syncthreads();
        bf16x8 av[4];
        #pragma unroll
        for (int i = 0; i < 4; ++i) av[i] = *(const bf16x8*)(smem + aaddr[i]);
        #pragma unroll
        for (int j = 0; j < 3; ++j) {
            bf16x8 bv = *(const bf16x8*)(smem + baddr[j]);
            #pragma unroll
            for (int i = 0; i < 4; ++i)
                acc[i][j] = __builtin_amdgcn_mfma_f32_16x16x32_bf16(av[i], bv, acc[i][j], 0, 0, 0);
        }
    }
    __syncthreads();   // staging regions -> per-wave epilogue scratch

    // ---------------- epilogue: full-pixel RQS ----------------
    // wave covers 64 px (pxb..pxb+63) x 2 channels (colg*2, colg*2+1).
    // 2 rounds x 1 task/lane; per-wave scratch 32 rows x 52 floats.
    float* scr = (float*)smem + w * 1664;
    float ldsum = 0.f;
    int pxl = lane & 31;
    int chsel = lane >> 5;            // 0/1
    int c = colg*2 + chsel;
    const float* bb3 = b3s + c*23;

    #pragma unroll 1
    for (int dri = 0; dri < 2; ++dri) {
        // stash 32-px half: quarters i = dri*2+q  (D: row m = quad*4+r, col = l15)
        #pragma unroll
        for (int q = 0; q < 2; ++q) {
            #pragma unroll
            for (int r = 0; r < 4; ++r) {
                int sr = q*16 + quad*4 + r;
                #pragma unroll
                for (int j = 0; j < 3; ++j)
                    scr[sr*52 + j*16 + l15] = acc[dri*2 + q][j][r];
            }
        }
        // per-wave private scratch: same-wave DS ordering suffices (no barrier)
        const float* P = scr + pxl*52 + chsel*24;
        float pr[24];
        *(float4v*)&pr[0]  = *(const float4v*)(P);
        *(float4v*)&pr[4]  = *(const float4v*)(P + 4);
        *(float4v*)&pr[8]  = *(const float4v*)(P + 8);
        *(float4v*)&pr[12] = *(const float4v*)(P + 12);
        *(float4v*)&pr[16] = *(const float4v*)(P + 16);
        *(float4v*)&pr[20] = *(const float4v*)(P + 20);
        float pa[23];
        #pragma unroll
        for (int j = 0; j < 23; ++j) pa[j] = pr[j] + bb3[j];

        int px = pxb + dri*32 + pxl;
        int gidx = ((b*12 + c) << 14) + (y << 7) + px;
        float xin = x[gidx];
        bool frozen = ((y + px) & 1) == 1;
        float xa = frozen ? 0.f : xin;
        float xf = frozen ? xin : 0.f;
        float xc = fminf(fmaxf(xa, -3.f), 3.f);
        bool inside = (xa >= -3.f) && (xa <= 3.f);

        // widths softmax + cumwidths + bin select
        float mw = pa[0];
        #pragma unroll
        for (int j = 1; j < 8; ++j) mw = fmaxf(mw, pa[j]);
        float ew[8]; float sw = 0.f;
        #pragma unroll
        for (int j = 0; j < 8; ++j) { ew[j] = __expf(pa[j] - mw); sw += ew[j]; }
        float Aw = 0.992f / sw;
        float run = 0.f, cwl = -3.f, icw = -3.f, iwid = 1.f;
        int idx = 0;
        #pragma unroll
        for (int j = 0; j < 8; ++j) {
            float wj = fmaf(Aw, ew[j], 0.001f);
            run += wj;
            float cwr = (j == 7) ? 3.f : fmaf(6.f, run, -3.f);
            if (xc >= cwl) { icw = cwl; iwid = cwr - cwl; idx = j; }
            cwl = cwr;
        }
        // heights softmax + cumheights at idx
        float mh = pa[8];
        #pragma unroll
        for (int j = 9; j < 16; ++j) mh = fmaxf(mh, pa[j]);
        float eh[8]; float sh = 0.f;
        #pragma unroll
        for (int j = 0; j < 8; ++j) { eh[j] = __expf(pa[8 + j] - mh); sh += eh[j]; }
        float Ah = 0.992f / sh;
        run = 0.f;
        float chl = -3.f, ich = 0.f, ihei = 1.f;
        #pragma unroll
        for (int j = 0; j < 8; ++j) {
            float hj = fmaf(Ah, eh[j], 0.001f);
            run += hj;
            float chr = (j == 7) ? 3.f : fmaf(6.f, run, -3.f);
            if (j == idx) { ich = chl; ihei = chr - chl; }
            chl = chr;
        }
        // derivatives: softplus only at selected slots (d[0]=d[8]=1 exactly)
        float v0 = 0.f, v1 = 0.f;
        bool h0 = false, h1 = false;
        #pragma unroll
        for (int j = 1; j < 8; ++j) {
            float v = pa[15 + j];
            if (j == idx)     { v0 = v; h0 = true; }
            if (j == idx + 1) { v1 = v; h1 = true; }
        }
        float sp0 = (v0 > 15.f) ? v0 : __logf(1.f + __expf(v0));
        float sp1 = (v1 > 15.f) ? v1 : __logf(1.f + __expf(v1));
        float d0 = h0 ? (0.001f + sp0) : 1.f;
        float d1 = h1 ? (0.001f + sp1) : 1.f;

        float dl = ihei / iwid;
        float th = (xc - icw) / iwid;
        float omt = 1.f - th;
        float t1 = th * omt;
        float num = ihei * (dl*th*th + d0*t1);
        float den = dl + (d0 + d1 - 2.f*dl)*t1;
        float yv = ich + num/den;
        float dnum = dl*dl*(d1*th*th + 2.f*dl*t1 + d0*omt*omt);
        float lad = __logf(dnum) - 2.f*__logf(den);

        out[gidx] = xf + (inside ? yv : xa);
        ldsum += inside ? lad : 0.f;
    }
    #pragma unroll
    for (int off = 32; off > 0; off >>= 1)
        ldsum += __shfl_down(ldsum, off, 64);
    if (lane == 0) atomicAdd(logdet_out + b, ldsum);
}

// ---------------------------------------------------------------------------
extern "C" void kernel_launch(void* const* d_in, const int* in_sizes, int n_in,
                              void* d_out, int out_size, void* d_ws, size_t ws_size,
                              hipStream_t stream)
{
    (void)in_sizes; (void)n_in; (void)out_size; (void)ws_size;
    const float* x    = (const float*)d_in[0];
    const float* ld   = (const float*)d_in[1];
    const float* cond = (const float*)d_in[2];
    const float* W1   = (const float*)d_in[3];
    const float* b1   = (const float*)d_in[4];
    const float* W2   = (const float*)d_in[5];
    const float* b2   = (const float*)d_in[6];
    const float* W3   = (const float*)d_in[7];
    const float* b3   = (const float*)d_in[8];
    float* out = (float*)d_out;
    char* ws = (char*)d_ws;

    short* zp   = (short*)(ws);                //  8,652,800 B  (16,130,130,16) bf16
    char*  h2p  = ws + 8652800;                // 34,611,200 B  (16,130,130,64) bf16
    short* W1sw = (short*)(ws + 43264000);     //     20,480 B
    short* W2sw = (short*)(ws + 43284480);     //      8,192 B
    short* W3sw = (short*)(ws + 43292672);     //    331,776 B
    char*  zerob= ws + 43624448;               //      1,024 B
    float* ldout = out + 12*HW*16;

    prep_weights<<<dim3(256), dim3(256), 0, stream>>>(
        W1, W2, W3, W1sw, W2sw, W3sw, h2p, (int4v*)zerob);
    pack_z<<<dim3(1057), dim3(256), 0, stream>>>(x, cond, ld, zp, ldout);
    conv12_kernel<<<dim3(2048), dim3(256), 0, stream>>>(
        (const char*)zp, (const char*)W1sw, (const char*)W2sw, b1, b2,
        (const char*)zerob, h2p);
    conv3_rqs_kernel<<<dim3(2048), dim3(768), 0, stream>>>(
        (const char*)h2p, (const char*)W3sw, b3, x, out, ldout);
}

// Round 5
// 446.772 us; speedup vs baseline: 2.4007x; 2.4007x over previous
//
#include <hip/hip_runtime.h>

#define HW (128*128)

typedef __bf16 bf16x8 __attribute__((ext_vector_type(8)));
typedef float  float4v __attribute__((ext_vector_type(4)));
typedef int    int4v   __attribute__((ext_vector_type(4)));
typedef int    int2v   __attribute__((ext_vector_type(2)));

static __device__ __forceinline__ short f2bf(float f) {
    unsigned u = __float_as_uint(f);
    unsigned r = (u + 0x7FFFu + ((u >> 16) & 1u)) >> 16;
    return (short)(r & 0xFFFFu);
}
static __device__ __forceinline__ int pack2(short a, short b) {
    return (int)((unsigned short)a | ((unsigned)(unsigned short)b << 16));
}
// async global->LDS, 16B per lane; LDS dest = wave-uniform base + lane*16
static __device__ __forceinline__ void async_cp16(const void* g, void* l) {
    __builtin_amdgcn_global_load_lds(
        (const __attribute__((address_space(1))) unsigned int*)g,
        (__attribute__((address_space(3))) unsigned int*)l, 16, 0, 0);
}

// ---------------------------------------------------------------------------
// prep: pre-swizzled bf16 weight streams (LDS-chunk order per K-step), zero
// buffer, h2p halo zeroing.
// Swizzle rule (64B rows, 4 chunks): LDS chunk (n,c) holds k-chunk c^((n>>1)&3).
// ---------------------------------------------------------------------------
__global__ __launch_bounds__(256) void prep_weights(
    const float* __restrict__ W1, const float* __restrict__ W2,
    const float* __restrict__ W3,
    short* __restrict__ W1sw, short* __restrict__ W2sw, short* __restrict__ W3sw,
    char* __restrict__ h2p, int4v* __restrict__ zerobuf)
{
    int tid = blockIdx.x * 256 + threadIdx.x;
    int stride = gridDim.x * 256;
    // W1sw: 5 steps x 256 chunks x 8 elems (k-chunk gc -> tap=2s+(gc>>1), ch0=(gc&1)*8)
    for (int i = tid; i < 5*256*8; i += stride) {
        int e = i & 7, q = (i >> 3) & 255, s = i >> 11;
        int n = q >> 2, c = q & 3;
        int gc = c ^ ((n >> 1) & 3);
        int tap = 2*s + (gc >> 1);
        int ch = (gc & 1)*8 + e;
        float v = 0.f;
        if (tap < 9) {
            int ky = (tap*11) >> 5; int kx = tap - 3*ky;
            v = W1[((n*16 + ch)*3 + ky)*3 + kx];
        }
        W1sw[i] = f2bf(v);
    }
    // W2sw: 2 x 256 x 8 (k = s*32 + gc*8 + e)
    for (int i = tid; i < 2*256*8; i += stride) {
        int e = i & 7, q = (i >> 3) & 255, s = i >> 11;
        int n = q >> 2, c = q & 3;
        int gc = c ^ ((n >> 1) & 3);
        int k = s*32 + gc*8 + e;
        W2sw[i] = f2bf(W2[n*64 + k]);
    }
    // W3sw: 18 x 1152 x 8 ; n = ch*24+j (j==23 pad), k = s*32+gc*8+e -> tap=k>>6, ci=k&63
    for (int i = tid; i < 18*1152*8; i += stride) {
        int e = i & 7;
        int q = (i >> 3) % 1152;
        int s = i / (1152*8);
        int n = q >> 2, c = q & 3;
        int gc = c ^ ((n >> 1) & 3);
        int k = s*32 + gc*8 + e;
        int tap = k >> 6, ci = k & 63;
        int ch = n / 24, j = n - 24*ch;
        float v = 0.f;
        if (j < 23) v = W3[((ch*23 + j)*64 + ci)*9 + tap];
        W3sw[i] = f2bf(v);
    }
    for (int i = tid; i < 64; i += stride) { int4v zz = {0,0,0,0}; zerobuf[i] = zz; }
    // h2p halo zero: 16 batches x 516 border px x 8 chunks
    for (int i = tid; i < 16*516*8; i += stride) {
        int cchunk = i & 7, pxi = (i >> 3) % 516, b = i / (516*8);
        int yy, xx;
        if (pxi < 130)      { yy = 0;   xx = pxi; }
        else if (pxi < 260) { yy = 129; xx = pxi - 130; }
        else if (pxi < 388) { yy = pxi - 260 + 1; xx = 0; }
        else                { yy = pxi - 388 + 1; xx = 129; }
        int4v zz = {0,0,0,0};
        *(int4v*)(h2p + (size_t)((b*130 + yy)*130 + xx)*128 + cchunk*16) = zz;
    }
}

// ---------------------------------------------------------------------------
// pack z with 1-px halo: (16,130,130,16ch) bf16; interior ch0-11 = masked x,
// ch12-15 = cond; halo rows/cols zero. Also init logdet outputs.
// ---------------------------------------------------------------------------
__global__ __launch_bounds__(256) void pack_z(
    const float* __restrict__ x, const float* __restrict__ cond,
    const float* __restrict__ logdet_in,
    short* __restrict__ zp, float* __restrict__ logdet_out)
{
    int id = blockIdx.x * 256 + threadIdx.x;
    if (id < 16) logdet_out[id] = logdet_in[id];
    if (id >= 16*130*130) return;
    int b = id / 16900;
    int rem = id - b*16900;
    int yy = rem / 130;
    int xx = rem - yy*130;
    short vs[16];
    #pragma unroll
    for (int c = 0; c < 16; ++c) vs[c] = 0;
    if (yy >= 1 && yy <= 128 && xx >= 1 && xx <= 128) {
        int pix = (yy - 1)*128 + (xx - 1);
        bool frozen = ((yy + xx) & 1) == 1;
        #pragma unroll
        for (int c = 0; c < 12; ++c)
            vs[c] = f2bf(frozen ? x[(b*12 + c)*HW + pix] : 0.f);
        #pragma unroll
        for (int c = 0; c < 4; ++c)
            vs[12 + c] = f2bf(cond[(b*4 + c)*HW + pix]);
    }
    int4v lo = { pack2(vs[0],vs[1]),  pack2(vs[2],vs[3]),
                 pack2(vs[4],vs[5]),  pack2(vs[6],vs[7]) };
    int4v hi = { pack2(vs[8],vs[9]),  pack2(vs[10],vs[11]),
                 pack2(vs[12],vs[13]),pack2(vs[14],vs[15]) };
    *(int4v*)(zp + id*16)     = lo;
    *(int4v*)(zp + id*16 + 8) = hi;
}

// ---------------------------------------------------------------------------
// fused conv1 (3x3, 16->64) + conv2 (1x1, 64->64). Block = one image row.
// Operands swapped: A = weights (M=out-ch), B = pixels (N=px) so D cols = px.
// LDS: z-tile [128px][32k] (8K) | W [64][32k] (4K) | h1/h2 tile [128px][64ch] (16K)
// ---------------------------------------------------------------------------
__global__ __launch_bounds__(256, 4) void conv12_kernel(
    const char* __restrict__ zp, const char* __restrict__ W1sw,
    const char* __restrict__ W2sw,
    const float* __restrict__ b1, const float* __restrict__ b2,
    const char* __restrict__ zerobuf, char* __restrict__ h2p)
{
    __shared__ __align__(16) char smem[28672];
    int t = threadIdx.x;
    int lane = t & 63, w = t >> 6;
    int l15 = lane & 15, quad = lane >> 4;
    int bid = blockIdx.x;
    int b = bid >> 7, y = bid & 127;
    int chb = (w >> 1) * 32;
    int pxb = (w & 1) * 64;
    unsigned wbase = (unsigned)__builtin_amdgcn_readfirstlane(w << 10);

    // staging constants: chunk q -> px=q>>2, c=q&3, gc=c^((px>>1)&3)
    int px1 = t >> 2;
    int gc1 = (t & 3) ^ ((px1 >> 1) & 3);
    int tl1 = gc1 >> 1, zoff1 = px1*32 + (gc1 & 1)*16;
    int q2 = t + 256;
    int px2 = q2 >> 2;
    int gc2 = (q2 & 3) ^ ((px2 >> 1) & 3);
    int tl2 = gc2 >> 1, zoff2 = px2*32 + (gc2 & 1)*16;

    int waddr[2], zaddr[4];
    #pragma unroll
    for (int i = 0; i < 2; ++i) {
        int n = chb + i*16 + l15;
        waddr[i] = 8192 + n*64 + ((quad ^ ((n >> 1) & 3)) << 4);
    }
    #pragma unroll
    for (int j = 0; j < 4; ++j) {
        int px = pxb + j*16 + l15;
        zaddr[j] = px*64 + ((quad ^ ((px >> 1) & 3)) << 4);
    }

    const char* zb = zp + (size_t)(b*16900)*32;
    const float4v z4 = {0.f,0.f,0.f,0.f};
    float4v acc[2][4];
    #pragma unroll
    for (int i = 0; i < 2; ++i)
        #pragma unroll
        for (int j = 0; j < 4; ++j) acc[i][j] = z4;

    // ---- conv1: 5 K-steps of 32 (taps 2s, 2s+1; tap 9 = zero pad) ----
    for (int s = 0; s < 5; ++s) {
        __syncthreads();
        int ta = 2*s + tl1;
        const char* g1;
        if (ta < 9) { int ky = (ta*11) >> 5; int kx = ta - 3*ky;
            g1 = zb + ((y + ky)*130 + kx)*32 + zoff1; }
        else g1 = zerobuf + (lane << 4);
        async_cp16(g1, smem + wbase);
        int tb = 2*s + tl2;
        const char* g2;
        if (tb < 9) { int ky = (tb*11) >> 5; int kx = tb - 3*ky;
            g2 = zb + ((y + ky)*130 + kx)*32 + zoff2; }
        else g2 = zerobuf + (lane << 4);
        async_cp16(g2, smem + 4096 + wbase);
        async_cp16(W1sw + s*4096 + (t << 4), smem + 8192 + wbase);
        __syncthreads();
        bf16x8 aw[2];
        #pragma unroll
        for (int i = 0; i < 2; ++i) aw[i] = *(const bf16x8*)(smem + waddr[i]);
        #pragma unroll
        for (int j = 0; j < 4; ++j) {
            bf16x8 bzv = *(const bf16x8*)(smem + zaddr[j]);
            #pragma unroll
            for (int i = 0; i < 2; ++i)
                acc[i][j] = __builtin_amdgcn_mfma_f32_16x16x32_bf16(aw[i], bzv, acc[i][j], 0, 0, 0);
        }
    }
    // ---- conv1 epilogue: bias+ReLU+bf16 -> h1 tile [px][64ch], 8-chunk XOR swizzle ----
    {
        #pragma unroll
        for (int i = 0; i < 2; ++i) {
            int ch0 = chb + i*16 + quad*4;
            float bb0 = b1[ch0], bb1 = b1[ch0+1], bb2 = b1[ch0+2], bb3 = b1[ch0+3];
            #pragma unroll
            for (int j = 0; j < 4; ++j) {
                int px = pxb + j*16 + l15;
                short s0 = f2bf(fmaxf(acc[i][j][0] + bb0, 0.f));
                short s1 = f2bf(fmaxf(acc[i][j][1] + bb1, 0.f));
                short s2 = f2bf(fmaxf(acc[i][j][2] + bb2, 0.f));
                short s3 = f2bf(fmaxf(acc[i][j][3] + bb3, 0.f));
                int2v pk = { pack2(s0, s1), pack2(s2, s3) };
                *(int2v*)(smem + 12288 + px*128 + (((ch0 >> 3) ^ (px & 7)) << 4) + ((ch0 & 7) << 1)) = pk;
            }
        }
    }
    // ---- conv2: 2 K-steps of 32 ----
    float4v acc2[2][4];
    #pragma unroll
    for (int i = 0; i < 2; ++i)
        #pragma unroll
        for (int j = 0; j < 4; ++j) acc2[i][j] = z4;
    for (int s = 0; s < 2; ++s) {
        __syncthreads();
        async_cp16(W2sw + s*4096 + (t << 4), smem + 8192 + wbase);
        __syncthreads();
        bf16x8 aw[2];
        #pragma unroll
        for (int i = 0; i < 2; ++i) aw[i] = *(const bf16x8*)(smem + waddr[i]);
        #pragma unroll
        for (int j = 0; j < 4; ++j) {
            int px = pxb + j*16 + l15;
            bf16x8 bh = *(const bf16x8*)(smem + 12288 + px*128 + (((s*4 + quad) ^ (px & 7)) << 4));
            #pragma unroll
            for (int i = 0; i < 2; ++i)
                acc2[i][j] = __builtin_amdgcn_mfma_f32_16x16x32_bf16(aw[i], bh, acc2[i][j], 0, 0, 0);
        }
    }
    __syncthreads();   // all h1 reads done; reuse tile region for h2
    {
        #pragma unroll
        for (int i = 0; i < 2; ++i) {
            int ch0 = chb + i*16 + quad*4;
            float bb0 = b2[ch0], bb1 = b2[ch0+1], bb2 = b2[ch0+2], bb3 = b2[ch0+3];
            #pragma unroll
            for (int j = 0; j < 4; ++j) {
                int px = pxb + j*16 + l15;
                short s0 = f2bf(fmaxf(acc2[i][j][0] + bb0, 0.f));
                short s1 = f2bf(fmaxf(acc2[i][j][1] + bb1, 0.f));
                short s2 = f2bf(fmaxf(acc2[i][j][2] + bb2, 0.f));
                short s3 = f2bf(fmaxf(acc2[i][j][3] + bb3, 0.f));
                int2v pk = { pack2(s0, s1), pack2(s2, s3) };
                *(int2v*)(smem + 12288 + px*128 + (((ch0 >> 3) ^ (px & 7)) << 4) + ((ch0 & 7) << 1)) = pk;
            }
        }
    }
    __syncthreads();
    // copy h2 tile to global (unswizzle on LDS read; coalesced global store)
    char* dst = h2p + ((size_t)(b*130 + y + 1)*130 + 1)*128;
    #pragma unroll
    for (int u = 0; u < 4; ++u) {
        int q = t + u*256;
        int px = q >> 3, g = q & 7;
        int4v v = *(const int4v*)(smem + 12288 + px*128 + ((g ^ (px & 7)) << 4));
        *(int4v*)(dst + px*128 + (g << 4)) = v;
    }
}

// ---------------------------------------------------------------------------
// RQS transform for one pixel given 23 params + x value. Returns y, adds lad.
// ---------------------------------------------------------------------------
static __device__ __forceinline__ float rqs_eval(
    const float* __restrict__ pa, float xin, bool frozen, float& ldsum)
{
    float xa = frozen ? 0.f : xin;
    float xf = frozen ? xin : 0.f;
    float xc = fminf(fmaxf(xa, -3.f), 3.f);
    bool inside = (xa >= -3.f) && (xa <= 3.f);

    // widths softmax + cumwidths + bin select
    float mw = pa[0];
    #pragma unroll
    for (int j = 1; j < 8; ++j) mw = fmaxf(mw, pa[j]);
    float ew[8]; float sw = 0.f;
    #pragma unroll
    for (int j = 0; j < 8; ++j) { ew[j] = __expf(pa[j] - mw); sw += ew[j]; }
    float Aw = 0.992f / sw;
    float run = 0.f, cwl = -3.f, icw = -3.f, iwid = 1.f;
    int idx = 0;
    #pragma unroll
    for (int j = 0; j < 8; ++j) {
        float wj = fmaf(Aw, ew[j], 0.001f);
        run += wj;
        float cwr = (j == 7) ? 3.f : fmaf(6.f, run, -3.f);
        if (xc >= cwl) { icw = cwl; iwid = cwr - cwl; idx = j; }
        cwl = cwr;
    }
    // heights softmax + cumheights at idx
    float mh = pa[8];
    #pragma unroll
    for (int j = 9; j < 16; ++j) mh = fmaxf(mh, pa[j]);
    float eh[8]; float sh = 0.f;
    #pragma unroll
    for (int j = 0; j < 8; ++j) { eh[j] = __expf(pa[8 + j] - mh); sh += eh[j]; }
    float Ah = 0.992f / sh;
    run = 0.f;
    float chl = -3.f, ich = 0.f, ihei = 1.f;
    #pragma unroll
    for (int j = 0; j < 8; ++j) {
        float hj = fmaf(Ah, eh[j], 0.001f);
        run += hj;
        float chr = (j == 7) ? 3.f : fmaf(6.f, run, -3.f);
        if (j == idx) { ich = chl; ihei = chr - chl; }
        chl = chr;
    }
    // derivatives: softplus only at selected slots (d[0]=d[8]=1 exactly)
    float v0 = 0.f, v1 = 0.f;
    bool h0 = false, h1 = false;
    #pragma unroll
    for (int j = 1; j < 8; ++j) {
        float v = pa[15 + j];
        if (j == idx)     { v0 = v; h0 = true; }
        if (j == idx + 1) { v1 = v; h1 = true; }
    }
    float sp0 = (v0 > 15.f) ? v0 : __logf(1.f + __expf(v0));
    float sp1 = (v1 > 15.f) ? v1 : __logf(1.f + __expf(v1));
    float d0 = h0 ? (0.001f + sp0) : 1.f;
    float d1 = h1 ? (0.001f + sp1) : 1.f;

    float dl = ihei / iwid;
    float th = (xc - icw) / iwid;
    float omt = 1.f - th;
    float t1 = th * omt;
    float num = ihei * (dl*th*th + d0*t1);
    float den = dl + (d0 + d1 - 2.f*dl)*t1;
    float yv = ich + num/den;
    float dnum = dl*dl*(d1*th*th + 2.f*dl*t1 + d0*omt*omt);
    float lad = __logf(dnum) - 2.f*__logf(den);

    ldsum += inside ? lad : 0.f;
    return xf + (inside ? yv : xa);
}

// ---------------------------------------------------------------------------
// conv3 (3x3, 64 -> 276 pad 288) fused with RQS + logdet.
// Block = one row, 768 threads = 12 waves: (px-half 2) x (col-group-of-48 6).
// Wave acc = 4x3 float4 = 48 regs. Epilogue dri-loop FULLY UNROLLED so acc
// indices are compile-time (runtime indexing demotes acc to scratch: R3/R4
// showed 5.7 GB of scratch WRITE_SIZE from exactly this).
// ---------------------------------------------------------------------------
__global__ __launch_bounds__(768, 3) void conv3_rqs_kernel(
    const char* __restrict__ h2p, const char* __restrict__ W3sw,
    const float* __restrict__ b3, const float* __restrict__ x,
    float* __restrict__ out, float* __restrict__ logdet_out)
{
    __shared__ __align__(16) char smem[80976];
    // staging: [0,8192) A-tile (128px x 64B) | [8192,26624) B-tile (1152 chunks)
    // epilogue: [0,79872) = 12 waves x 32rows x 52 floats | [79872,80976) b3
    int t = threadIdx.x;
    int lane = t & 63, w = t >> 6;
    int l15 = lane & 15, quad = lane >> 4;
    int bid = blockIdx.x;
    int b = bid >> 7, y = bid & 127;

    float* b3s = (float*)(smem + 79872);
    if (t < 276) b3s[t] = b3[t];

    int p = (w >= 6) ? 1 : 0;
    int colg = w - 6*p;        // 0..5
    int pxb = p << 6;          // 0 or 64
    int cb = colg * 48;

    int aaddr[4], baddr[3];
    #pragma unroll
    for (int i = 0; i < 4; ++i) {
        int row = pxb + i*16 + l15;
        aaddr[i] = row*64 + ((quad ^ ((row >> 1) & 3)) << 4);
    }
    #pragma unroll
    for (int j = 0; j < 3; ++j) {
        int n = cb + j*16 + l15;
        baddr[j] = 8192 + n*64 + ((quad ^ ((n >> 1) & 3)) << 4);
    }

    // A staging (waves 0..7): chunk t -> px = t>>2, gc = (t&3)^((px>>1)&3)
    int pxs = t >> 2;
    int gcs = (t & 3) ^ ((pxs >> 1) & 3);
    int offA = pxs*128 + gcs*16;
    unsigned wbase = (unsigned)__builtin_amdgcn_readfirstlane(w << 10);

    const float4v z4 = {0.f,0.f,0.f,0.f};
    float4v acc[4][3];
    #pragma unroll
    for (int i = 0; i < 4; ++i)
        #pragma unroll
        for (int j = 0; j < 3; ++j) acc[i][j] = z4;

    const char* h2pb = h2p + (size_t)(b*130)*130*128;
    for (int s = 0; s < 18; ++s) {
        int tap = s >> 1, kh = s & 1;
        int td3 = (tap*11) >> 5;
        int tm3 = tap - 3*td3;
        const char* sbA = h2pb + ((y + td3)*130 + tm3)*128 + kh*64;
        const char* sbB = W3sw + s*18432;
        __syncthreads();
        if (w < 8)  async_cp16(sbA + offA, smem + wbase);
        async_cp16(sbB + (t << 4), smem + 8192 + wbase);
        if (w < 6)  async_cp16(sbB + 12288 + (t << 4), smem + 20480 + wbase);
        __syncthreads();
        bf16x8 av[4];
        #pragma unroll
        for (int i = 0; i < 4; ++i) av[i] = *(const bf16x8*)(smem + aaddr[i]);
        #pragma unroll
        for (int j = 0; j < 3; ++j) {
            bf16x8 bv = *(const bf16x8*)(smem + baddr[j]);
            #pragma unroll
            for (int i = 0; i < 4; ++i)
                acc[i][j] = __builtin_amdgcn_mfma_f32_16x16x32_bf16(av[i], bv, acc[i][j], 0, 0, 0);
        }
    }
    __syncthreads();   // staging regions -> per-wave epilogue scratch

    // ---------------- epilogue: full-pixel RQS, FULLY UNROLLED ----------------
    // wave covers 64 px (pxb..pxb+63) x 2 channels (colg*2, colg*2+1).
    float* scr = (float*)smem + w * 1664;    // 32 rows x 52 floats per wave
    float ldsum = 0.f;
    int pxl = lane & 31;
    int chsel = lane >> 5;            // 0/1
    int c = colg*2 + chsel;
    const float* bb3 = b3s + c*23;

    #pragma unroll
    for (int dri = 0; dri < 2; ++dri) {
        // stash 32-px half: quarters i = dri*2+q  (D: row m = quad*4+r, col = l15)
        #pragma unroll
        for (int q = 0; q < 2; ++q) {
            #pragma unroll
            for (int r = 0; r < 4; ++r) {
                int sr = q*16 + quad*4 + r;
                #pragma unroll
                for (int j = 0; j < 3; ++j)
                    scr[sr*52 + j*16 + l15] = acc[dri*2 + q][j][r];
            }
        }
        // per-wave private scratch: same-wave DS ordering suffices (no barrier)
        const float* P = scr + pxl*52 + chsel*24;
        float pa[23];
        {
            float pr[24];
            *(float4v*)&pr[0]  = *(const float4v*)(P);
            *(float4v*)&pr[4]  = *(const float4v*)(P + 4);
            *(float4v*)&pr[8]  = *(const float4v*)(P + 8);
            *(float4v*)&pr[12] = *(const float4v*)(P + 12);
            *(float4v*)&pr[16] = *(const float4v*)(P + 16);
            *(float4v*)&pr[20] = *(const float4v*)(P + 20);
            #pragma unroll
            for (int j = 0; j < 23; ++j) pa[j] = pr[j] + bb3[j];
        }
        int px = pxb + dri*32 + pxl;
        int gidx = ((b*12 + c) << 14) + (y << 7) + px;
        float xin = x[gidx];
        bool frozen = ((y + px) & 1) == 1;
        out[gidx] = rqs_eval(pa, xin, frozen, ldsum);
    }
    #pragma unroll
    for (int off = 32; off > 0; off >>= 1)
        ldsum += __shfl_down(ldsum, off, 64);
    if (lane == 0) atomicAdd(logdet_out + b, ldsum);
}

// ---------------------------------------------------------------------------
extern "C" void kernel_launch(void* const* d_in, const int* in_sizes, int n_in,
                              void* d_out, int out_size, void* d_ws, size_t ws_size,
                              hipStream_t stream)
{
    (void)in_sizes; (void)n_in; (void)out_size; (void)ws_size;
    const float* x    = (const float*)d_in[0];
    const float* ld   = (const float*)d_in[1];
    const float* cond = (const float*)d_in[2];
    const float* W1   = (const float*)d_in[3];
    const float* b1   = (const float*)d_in[4];
    const float* W2   = (const float*)d_in[5];
    const float* b2   = (const float*)d_in[6];
    const float* W3   = (const float*)d_in[7];
    const float* b3   = (const float*)d_in[8];
    float* out = (float*)d_out;
    char* ws = (char*)d_ws;

    short* zp   = (short*)(ws);                //  8,652,800 B  (16,130,130,16) bf16
    char*  h2p  = ws + 8652800;                // 34,611,200 B  (16,130,130,64) bf16
    short* W1sw = (short*)(ws + 43264000);     //     20,480 B
    short* W2sw = (short*)(ws + 43284480);     //      8,192 B
    short* W3sw = (short*)(ws + 43292672);     //    331,776 B
    char*  zerob= ws + 43624448;               //      1,024 B
    float* ldout = out + 12*HW*16;

    prep_weights<<<dim3(256), dim3(256), 0, stream>>>(
        W1, W2, W3, W1sw, W2sw, W3sw, h2p, (int4v*)zerob);
    pack_z<<<dim3(1057), dim3(256), 0, stream>>>(x, cond, ld, zp, ldout);
    conv12_kernel<<<dim3(2048), dim3(256), 0, stream>>>(
        (const char*)zp, (const char*)W1sw, (const char*)W2sw, b1, b2,
        (const char*)zerob, h2p);
    conv3_rqs_kernel<<<dim3(2048), dim3(768), 0, stream>>>(
        (const char*)h2p, (const char*)W3sw, b3, x, out, ldout);
}

// Round 6
// 216.547 us; speedup vs baseline: 4.9531x; 2.0632x over previous
//
#include <hip/hip_runtime.h>

#define HW (128*128)

typedef __bf16 bf16x8 __attribute__((ext_vector_type(8)));
typedef float  float4v __attribute__((ext_vector_type(4)));
typedef int    int4v   __attribute__((ext_vector_type(4)));
typedef int    int2v   __attribute__((ext_vector_type(2)));

static __device__ __forceinline__ short f2bf(float f) {
    unsigned u = __float_as_uint(f);
    unsigned r = (u + 0x7FFFu + ((u >> 16) & 1u)) >> 16;
    return (short)(r & 0xFFFFu);
}
static __device__ __forceinline__ int pack2(short a, short b) {
    return (int)((unsigned short)a | ((unsigned)(unsigned short)b << 16));
}
// async global->LDS, 16B per lane; LDS dest = wave-uniform base + lane*16
static __device__ __forceinline__ void async_cp16(const void* g, void* l) {
    __builtin_amdgcn_global_load_lds(
        (const __attribute__((address_space(1))) unsigned int*)g,
        (__attribute__((address_space(3))) unsigned int*)l, 16, 0, 0);
}

// ---------------------------------------------------------------------------
// prep: pre-swizzled bf16 weight streams, zero buffer, h2p halo zeroing.
// W1sw/W2sw: 4-chunk XOR swizzle c^((n>>1)&3) (conv12, unchanged).
// W3sw NEW: per-tap layout [tap][n][c][e] (n<288=ch*24+j, 8 chunks of 8 k-elems),
//           chunk c holds k-chunk c^(n&7), k = ci in [0,64) of this tap.
// ---------------------------------------------------------------------------
__global__ __launch_bounds__(256) void prep_weights(
    const float* __restrict__ W1, const float* __restrict__ W2,
    const float* __restrict__ W3,
    short* __restrict__ W1sw, short* __restrict__ W2sw, short* __restrict__ W3sw,
    char* __restrict__ h2p, int4v* __restrict__ zerobuf)
{
    int tid = blockIdx.x * 256 + threadIdx.x;
    int stride = gridDim.x * 256;
    for (int i = tid; i < 5*256*8; i += stride) {
        int e = i & 7, q = (i >> 3) & 255, s = i >> 11;
        int n = q >> 2, c = q & 3;
        int gc = c ^ ((n >> 1) & 3);
        int tap = 2*s + (gc >> 1);
        int ch = (gc & 1)*8 + e;
        float v = 0.f;
        if (tap < 9) {
            int ky = (tap*11) >> 5; int kx = tap - 3*ky;
            v = W1[((n*16 + ch)*3 + ky)*3 + kx];
        }
        W1sw[i] = f2bf(v);
    }
    for (int i = tid; i < 2*256*8; i += stride) {
        int e = i & 7, q = (i >> 3) & 255, s = i >> 11;
        int n = q >> 2, c = q & 3;
        int gc = c ^ ((n >> 1) & 3);
        int k = s*32 + gc*8 + e;
        W2sw[i] = f2bf(W2[n*64 + k]);
    }
    // W3sw: 9 taps x 288 n x 8 chunks x 8 elems
    for (int i = tid; i < 9*288*64; i += stride) {
        int e = i & 7;
        int c = (i >> 3) & 7;
        int r = i >> 6;
        int tap = r / 288;
        int n = r - tap*288;
        int ch = n / 24, jj = n - 24*ch;
        int ci = ((c ^ (n & 7)) << 3) + e;
        float v = 0.f;
        if (jj < 23) v = W3[((ch*23 + jj)*64 + ci)*9 + tap];
        W3sw[i] = f2bf(v);
    }
    for (int i = tid; i < 64; i += stride) { int4v zz = {0,0,0,0}; zerobuf[i] = zz; }
    // h2p halo zero: 16 batches x 516 border px x 8 chunks
    for (int i = tid; i < 16*516*8; i += stride) {
        int cchunk = i & 7, pxi = (i >> 3) % 516, b = i / (516*8);
        int yy, xx;
        if (pxi < 130)      { yy = 0;   xx = pxi; }
        else if (pxi < 260) { yy = 129; xx = pxi - 130; }
        else if (pxi < 388) { yy = pxi - 260 + 1; xx = 0; }
        else                { yy = pxi - 388 + 1; xx = 129; }
        int4v zz = {0,0,0,0};
        *(int4v*)(h2p + (size_t)((b*130 + yy)*130 + xx)*128 + cchunk*16) = zz;
    }
}

// ---------------------------------------------------------------------------
// pack z with 1-px halo; zero logdet partial slots.
// ---------------------------------------------------------------------------
__global__ __launch_bounds__(256) void pack_z(
    const float* __restrict__ x, const float* __restrict__ cond,
    short* __restrict__ zp, float* __restrict__ ldslots)
{
    int id = blockIdx.x * 256 + threadIdx.x;
    if (id < 1024) ldslots[id] = 0.f;
    if (id >= 16*130*130) return;
    int b = id / 16900;
    int rem = id - b*16900;
    int yy = rem / 130;
    int xx = rem - yy*130;
    short vs[16];
    #pragma unroll
    for (int c = 0; c < 16; ++c) vs[c] = 0;
    if (yy >= 1 && yy <= 128 && xx >= 1 && xx <= 128) {
        int pix = (yy - 1)*128 + (xx - 1);
        bool frozen = ((yy + xx) & 1) == 1;
        #pragma unroll
        for (int c = 0; c < 12; ++c)
            vs[c] = f2bf(frozen ? x[(b*12 + c)*HW + pix] : 0.f);
        #pragma unroll
        for (int c = 0; c < 4; ++c)
            vs[12 + c] = f2bf(cond[(b*4 + c)*HW + pix]);
    }
    int4v lo = { pack2(vs[0],vs[1]),  pack2(vs[2],vs[3]),
                 pack2(vs[4],vs[5]),  pack2(vs[6],vs[7]) };
    int4v hi = { pack2(vs[8],vs[9]),  pack2(vs[10],vs[11]),
                 pack2(vs[12],vs[13]),pack2(vs[14],vs[15]) };
    *(int4v*)(zp + id*16)     = lo;
    *(int4v*)(zp + id*16 + 8) = hi;
}

// ---------------------------------------------------------------------------
// fused conv1 (3x3, 16->64) + conv2 (1x1, 64->64). Block = one image row.
// bid decode XCD-swizzled: b = bid&15 pins batch to one XCD's L2.
// ---------------------------------------------------------------------------
__global__ __launch_bounds__(256, 4) void conv12_kernel(
    const char* __restrict__ zp, const char* __restrict__ W1sw,
    const char* __restrict__ W2sw,
    const float* __restrict__ b1, const float* __restrict__ b2,
    const char* __restrict__ zerobuf, char* __restrict__ h2p)
{
    __shared__ __align__(16) char smem[28672];
    int t = threadIdx.x;
    int lane = t & 63, w = t >> 6;
    int l15 = lane & 15, quad = lane >> 4;
    int bid = blockIdx.x;
    int b = bid & 15, y = bid >> 4;
    int chb = (w >> 1) * 32;
    int pxb = (w & 1) * 64;
    unsigned wbase = (unsigned)__builtin_amdgcn_readfirstlane(w << 10);

    int px1 = t >> 2;
    int gc1 = (t & 3) ^ ((px1 >> 1) & 3);
    int tl1 = gc1 >> 1, zoff1 = px1*32 + (gc1 & 1)*16;
    int q2 = t + 256;
    int px2 = q2 >> 2;
    int gc2 = (q2 & 3) ^ ((px2 >> 1) & 3);
    int tl2 = gc2 >> 1, zoff2 = px2*32 + (gc2 & 1)*16;

    int waddr[2], zaddr[4];
    #pragma unroll
    for (int i = 0; i < 2; ++i) {
        int n = chb + i*16 + l15;
        waddr[i] = 8192 + n*64 + ((quad ^ ((n >> 1) & 3)) << 4);
    }
    #pragma unroll
    for (int j = 0; j < 4; ++j) {
        int px = pxb + j*16 + l15;
        zaddr[j] = px*64 + ((quad ^ ((px >> 1) & 3)) << 4);
    }

    const char* zb = zp + (size_t)(b*16900)*32;
    const float4v z4 = {0.f,0.f,0.f,0.f};
    float4v acc[2][4];
    #pragma unroll
    for (int i = 0; i < 2; ++i)
        #pragma unroll
        for (int j = 0; j < 4; ++j) acc[i][j] = z4;

    for (int s = 0; s < 5; ++s) {
        __syncthreads();
        int ta = 2*s + tl1;
        const char* g1;
        if (ta < 9) { int ky = (ta*11) >> 5; int kx = ta - 3*ky;
            g1 = zb + ((y + ky)*130 + kx)*32 + zoff1; }
        else g1 = zerobuf + (lane << 4);
        async_cp16(g1, smem + wbase);
        int tb = 2*s + tl2;
        const char* g2;
        if (tb < 9) { int ky = (tb*11) >> 5; int kx = tb - 3*ky;
            g2 = zb + ((y + ky)*130 + kx)*32 + zoff2; }
        else g2 = zerobuf + (lane << 4);
        async_cp16(g2, smem + 4096 + wbase);
        async_cp16(W1sw + s*4096 + (t << 4), smem + 8192 + wbase);
        __syncthreads();
        bf16x8 aw[2];
        #pragma unroll
        for (int i = 0; i < 2; ++i) aw[i] = *(const bf16x8*)(smem + waddr[i]);
        #pragma unroll
        for (int j = 0; j < 4; ++j) {
            bf16x8 bzv = *(const bf16x8*)(smem + zaddr[j]);
            #pragma unroll
            for (int i = 0; i < 2; ++i)
                acc[i][j] = __builtin_amdgcn_mfma_f32_16x16x32_bf16(aw[i], bzv, acc[i][j], 0, 0, 0);
        }
    }
    {
        #pragma unroll
        for (int i = 0; i < 2; ++i) {
            int ch0 = chb + i*16 + quad*4;
            float bb0 = b1[ch0], bb1 = b1[ch0+1], bb2 = b1[ch0+2], bb3 = b1[ch0+3];
            #pragma unroll
            for (int j = 0; j < 4; ++j) {
                int px = pxb + j*16 + l15;
                short s0 = f2bf(fmaxf(acc[i][j][0] + bb0, 0.f));
                short s1 = f2bf(fmaxf(acc[i][j][1] + bb1, 0.f));
                short s2 = f2bf(fmaxf(acc[i][j][2] + bb2, 0.f));
                short s3 = f2bf(fmaxf(acc[i][j][3] + bb3, 0.f));
                int2v pk = { pack2(s0, s1), pack2(s2, s3) };
                *(int2v*)(smem + 12288 + px*128 + (((ch0 >> 3) ^ (px & 7)) << 4) + ((ch0 & 7) << 1)) = pk;
            }
        }
    }
    float4v acc2[2][4];
    #pragma unroll
    for (int i = 0; i < 2; ++i)
        #pragma unroll
        for (int j = 0; j < 4; ++j) acc2[i][j] = z4;
    for (int s = 0; s < 2; ++s) {
        __syncthreads();
        async_cp16(W2sw + s*4096 + (t << 4), smem + 8192 + wbase);
        __syncthreads();
        bf16x8 aw[2];
        #pragma unroll
        for (int i = 0; i < 2; ++i) aw[i] = *(const bf16x8*)(smem + waddr[i]);
        #pragma unroll
        for (int j = 0; j < 4; ++j) {
            int px = pxb + j*16 + l15;
            bf16x8 bh = *(const bf16x8*)(smem + 12288 + px*128 + (((s*4 + quad) ^ (px & 7)) << 4));
            #pragma unroll
            for (int i = 0; i < 2; ++i)
                acc2[i][j] = __builtin_amdgcn_mfma_f32_16x16x32_bf16(aw[i], bh, acc2[i][j], 0, 0, 0);
        }
    }
    __syncthreads();
    {
        #pragma unroll
        for (int i = 0; i < 2; ++i) {
            int ch0 = chb + i*16 + quad*4;
            float bb0 = b2[ch0], bb1 = b2[ch0+1], bb2 = b2[ch0+2], bb3 = b2[ch0+3];
            #pragma unroll
            for (int j = 0; j < 4; ++j) {
                int px = pxb + j*16 + l15;
                short s0 = f2bf(fmaxf(acc2[i][j][0] + bb0, 0.f));
                short s1 = f2bf(fmaxf(acc2[i][j][1] + bb1, 0.f));
                short s2 = f2bf(fmaxf(acc2[i][j][2] + bb2, 0.f));
                short s3 = f2bf(fmaxf(acc2[i][j][3] + bb3, 0.f));
                int2v pk = { pack2(s0, s1), pack2(s2, s3) };
                *(int2v*)(smem + 12288 + px*128 + (((ch0 >> 3) ^ (px & 7)) << 4) + ((ch0 & 7) << 1)) = pk;
            }
        }
    }
    __syncthreads();
    char* dst = h2p + ((size_t)(b*130 + y + 1)*130 + 1)*128;
    #pragma unroll
    for (int u = 0; u < 4; ++u) {
        int q = t + u*256;
        int px = q >> 3, g = q & 7;
        int4v v = *(const int4v*)(smem + 12288 + px*128 + ((g ^ (px & 7)) << 4));
        *(int4v*)(dst + px*128 + (g << 4)) = v;
    }
}

// ---------------------------------------------------------------------------
// RQS transform for one pixel given 23 params + x value. Returns y, adds lad.
// ---------------------------------------------------------------------------
static __device__ __forceinline__ float rqs_eval(
    const float* __restrict__ pa, float xin, bool frozen, float& ldsum)
{
    float xa = frozen ? 0.f : xin;
    float xf = frozen ? xin : 0.f;
    float xc = fminf(fmaxf(xa, -3.f), 3.f);
    bool inside = (xa >= -3.f) && (xa <= 3.f);

    float mw = pa[0];
    #pragma unroll
    for (int j = 1; j < 8; ++j) mw = fmaxf(mw, pa[j]);
    float ew[8]; float sw = 0.f;
    #pragma unroll
    for (int j = 0; j < 8; ++j) { ew[j] = __expf(pa[j] - mw); sw += ew[j]; }
    float Aw = 0.992f / sw;
    float run = 0.f, cwl = -3.f, icw = -3.f, iwid = 1.f;
    int idx = 0;
    #pragma unroll
    for (int j = 0; j < 8; ++j) {
        float wj = fmaf(Aw, ew[j], 0.001f);
        run += wj;
        float cwr = (j == 7) ? 3.f : fmaf(6.f, run, -3.f);
        if (xc >= cwl) { icw = cwl; iwid = cwr - cwl; idx = j; }
        cwl = cwr;
    }
    float mh = pa[8];
    #pragma unroll
    for (int j = 9; j < 16; ++j) mh = fmaxf(mh, pa[j]);
    float eh[8]; float sh = 0.f;
    #pragma unroll
    for (int j = 0; j < 8; ++j) { eh[j] = __expf(pa[8 + j] - mh); sh += eh[j]; }
    float Ah = 0.992f / sh;
    run = 0.f;
    float chl = -3.f, ich = 0.f, ihei = 1.f;
    #pragma unroll
    for (int j = 0; j < 8; ++j) {
        float hj = fmaf(Ah, eh[j], 0.001f);
        run += hj;
        float chr = (j == 7) ? 3.f : fmaf(6.f, run, -3.f);
        if (j == idx) { ich = chl; ihei = chr - chl; }
        chl = chr;
    }
    float v0 = 0.f, v1 = 0.f;
    bool h0 = false, h1 = false;
    #pragma unroll
    for (int j = 1; j < 8; ++j) {
        float v = pa[15 + j];
        if (j == idx)     { v0 = v; h0 = true; }
        if (j == idx + 1) { v1 = v; h1 = true; }
    }
    float sp0 = (v0 > 15.f) ? v0 : __logf(1.f + __expf(v0));
    float sp1 = (v1 > 15.f) ? v1 : __logf(1.f + __expf(v1));
    float d0 = h0 ? (0.001f + sp0) : 1.f;
    float d1 = h1 ? (0.001f + sp1) : 1.f;

    float dl = ihei / iwid;
    float th = (xc - icw) / iwid;
    float omt = 1.f - th;
    float t1 = th * omt;
    float num = ihei * (dl*th*th + d0*t1);
    float den = dl + (d0 + d1 - 2.f*dl)*t1;
    float yv = ich + num/den;
    float dnum = dl*dl*(d1*th*th + 2.f*dl*t1 + d0*omt*omt);
    float lad = __logf(dnum) - 2.f*__logf(den);

    ldsum += inside ? lad : 0.f;
    return xf + (inside ? yv : xa);
}

// ---------------------------------------------------------------------------
// conv3 (3x3, 64 -> 276 pad 288) fused with RQS.
// Block = 256 thr (4 waves), tile 64 px x 96 cols. Grid 12288 = 16b x 128y
// x 2 px-halves x 3 col-groups, XCD-swizzled (b = bid&15 -> batch-pinned L2).
// 9 per-tap stages (k=64): A 8KB + B 12KB staged per stage, 24 MFMA/wave.
// LDS 25.6 KB -> 6 blocks/CU co-resident (launch_bounds cap 85 VGPR).
// ---------------------------------------------------------------------------
__global__ __launch_bounds__(256, 6) void conv3_rqs_kernel(
    const char* __restrict__ h2p, const char* __restrict__ W3sw,
    const float* __restrict__ b3, const float* __restrict__ x,
    float* __restrict__ out, float* __restrict__ ldslots)
{
    __shared__ __align__(16) char smem[25600];
    // staging: [0,8192) A-tile 64px x 128B | [8192,20480) B-tile 96n x 128B
    // epilogue (aliased): [0,25600) scr 64px x 100 floats
    int t = threadIdx.x;
    int lane = t & 63, w = t >> 6;
    int l15 = lane & 15, quad = lane >> 4;
    int bid = blockIdx.x;
    int b = bid & 15;
    int r0 = bid >> 4;
    int cg = r0 % 3;
    int r1 = r0 / 3;
    int ph = r1 & 1;
    int y = r1 >> 1;

    int u = w & 1, v = w >> 1;   // px-sub (32), col-sub (48)

    int aaddr[2], baddr[3];
    #pragma unroll
    for (int i = 0; i < 2; ++i) {
        int row = u*32 + i*16 + l15;
        aaddr[i] = row*128 + ((quad ^ (row & 7)) << 4);
    }
    #pragma unroll
    for (int j = 0; j < 3; ++j) {
        int nl = v*48 + j*16 + l15;
        baddr[j] = 8192 + nl*128 + ((quad ^ (nl & 7)) << 4);
    }

    // A staging offsets (2 rounds of 256 chunks)
    int pxA0 = t >> 3, cA0 = t & 7;
    int offA0 = pxA0*128 + ((cA0 ^ (pxA0 & 7)) << 4);
    int q1 = t + 256;
    int pxA1 = q1 >> 3, cA1 = q1 & 7;
    int offA1 = pxA1*128 + ((cA1 ^ (pxA1 & 7)) << 4);
    unsigned wbase = (unsigned)__builtin_amdgcn_readfirstlane(w << 10);

    const float4v z4 = {0.f,0.f,0.f,0.f};
    float4v acc[2][3];
    #pragma unroll
    for (int i = 0; i < 2; ++i)
        #pragma unroll
        for (int j = 0; j < 3; ++j) acc[i][j] = z4;

    const char* h2pb = h2p + (size_t)(b*130)*130*128 + ph*8192;
    const char* W3b = W3sw + cg*12288;
    for (int tap = 0; tap < 9; ++tap) {
        int ty = (tap*11) >> 5;
        int tx = tap - 3*ty;
        const char* sbA = h2pb + ((y + ty)*130 + tx)*128;
        const char* sbB = W3b + tap*36864;
        __syncthreads();
        async_cp16(sbA + offA0, smem + wbase);
        async_cp16(sbA + offA1, smem + 4096 + wbase);
        async_cp16(sbB + (t << 4),        smem + 8192 + wbase);
        async_cp16(sbB + 4096 + (t << 4), smem + 12288 + wbase);
        async_cp16(sbB + 8192 + (t << 4), smem + 16384 + wbase);
        __syncthreads();
        #pragma unroll
        for (int kh = 0; kh < 2; ++kh) {
            int kx = kh << 6;
            bf16x8 av[2];
            #pragma unroll
            for (int i = 0; i < 2; ++i)
                av[i] = *(const bf16x8*)(smem + (aaddr[i] ^ kx));
            #pragma unroll
            for (int j = 0; j < 3; ++j) {
                bf16x8 bv = *(const bf16x8*)(smem + (baddr[j] ^ kx));
                #pragma unroll
                for (int i = 0; i < 2; ++i)
                    acc[i][j] = __builtin_amdgcn_mfma_f32_16x16x32_bf16(av[i], bv, acc[i][j], 0, 0, 0);
            }
        }
    }
    __syncthreads();   // staging reads done -> reuse LDS as epilogue scratch

    // ---------------- epilogue: block-wide transpose + RQS, 1 task/thread ----
    float* scr = (float*)smem;   // [64 px][100] (stride 100: quad writes 2-way)
    #pragma unroll
    for (int i = 0; i < 2; ++i)
        #pragma unroll
        for (int j = 0; j < 3; ++j)
            #pragma unroll
            for (int r = 0; r < 4; ++r) {
                int row = u*32 + i*16 + quad*4 + r;
                int col = v*48 + j*16 + l15;
                scr[row*100 + col] = acc[i][j][r];
            }
    __syncthreads();

    int px = t & 63;
    int chl = w;                 // 0..3
    int c = cg*4 + chl;
    const float* P = scr + px*100 + chl*24;
    float pa[23];
    {
        float pr[24];
        *(float4v*)&pr[0]  = *(const float4v*)(P);
        *(float4v*)&pr[4]  = *(const float4v*)(P + 4);
        *(float4v*)&pr[8]  = *(const float4v*)(P + 8);
        *(float4v*)&pr[12] = *(const float4v*)(P + 12);
        *(float4v*)&pr[16] = *(const float4v*)(P + 16);
        *(float4v*)&pr[20] = *(const float4v*)(P + 20);
        const float* bb3 = b3 + c*23;
        #pragma unroll
        for (int j = 0; j < 23; ++j) pa[j] = pr[j] + bb3[j];
    }
    int pxg = ph*64 + px;
    int gidx = ((b*12 + c) << 14) + (y << 7) + pxg;
    float xin = x[gidx];
    bool frozen = ((y + pxg) & 1) == 1;
    float ldsum = 0.f;
    out[gidx] = rqs_eval(pa, xin, frozen, ldsum);

    #pragma unroll
    for (int off = 32; off > 0; off >>= 1)
        ldsum += __shfl_down(ldsum, off, 64);
    if (lane == 0) atomicAdd(ldslots + b*64 + ((bid >> 4) & 63), ldsum);
}

// ---------------------------------------------------------------------------
// final logdet reduce: 16 blocks x 64 lanes.
// ---------------------------------------------------------------------------
__global__ __launch_bounds__(64) void logdet_reduce(
    const float* __restrict__ ldslots, const float* __restrict__ ld_in,
    float* __restrict__ ldout)
{
    int b = blockIdx.x;
    int lane = threadIdx.x;
    float s = ldslots[b*64 + lane];
    #pragma unroll
    for (int off = 32; off > 0; off >>= 1)
        s += __shfl_down(s, off, 64);
    if (lane == 0) ldout[b] = ld_in[b] + s;
}

// ---------------------------------------------------------------------------
extern "C" void kernel_launch(void* const* d_in, const int* in_sizes, int n_in,
                              void* d_out, int out_size, void* d_ws, size_t ws_size,
                              hipStream_t stream)
{
    (void)in_sizes; (void)n_in; (void)out_size; (void)ws_size;
    const float* x    = (const float*)d_in[0];
    const float* ld   = (const float*)d_in[1];
    const float* cond = (const float*)d_in[2];
    const float* W1   = (const float*)d_in[3];
    const float* b1   = (const float*)d_in[4];
    const float* W2   = (const float*)d_in[5];
    const float* b2   = (const float*)d_in[6];
    const float* W3   = (const float*)d_in[7];
    const float* b3   = (const float*)d_in[8];
    float* out = (float*)d_out;
    char* ws = (char*)d_ws;

    short* zp     = (short*)(ws);              //  8,652,800 B
    char*  h2p    = ws + 8652800;              // 34,611,200 B
    short* W1sw   = (short*)(ws + 43264000);   //     20,480 B
    short* W2sw   = (short*)(ws + 43284480);   //      8,192 B
    short* W3sw   = (short*)(ws + 43292672);   //    331,776 B
    char*  zerob  = ws + 43624448;             //      1,024 B
    float* ldslots= (float*)(ws + 43625472);   //      4,096 B
    float* ldout  = out + 12*HW*16;

    prep_weights<<<dim3(256), dim3(256), 0, stream>>>(
        W1, W2, W3, W1sw, W2sw, W3sw, h2p, (int4v*)zerob);
    pack_z<<<dim3(1057), dim3(256), 0, stream>>>(x, cond, zp, ldslots);
    conv12_kernel<<<dim3(2048), dim3(256), 0, stream>>>(
        (const char*)zp, (const char*)W1sw, (const char*)W2sw, b1, b2,
        (const char*)zerob, h2p);
    conv3_rqs_kernel<<<dim3(12288), dim3(256), 0, stream>>>(
        (const char*)h2p, (const char*)W3sw, b3, x, out, ldslots);
    logdet_reduce<<<dim3(16), dim3(64), 0, stream>>>(ldslots, ld, ldout);
}

// Round 7
// 209.912 us; speedup vs baseline: 5.1096x; 1.0316x over previous
//
#include <hip/hip_runtime.h>

#define HW (128*128)

typedef __bf16 bf16x8 __attribute__((ext_vector_type(8)));
typedef float  float4v __attribute__((ext_vector_type(4)));
typedef int    int4v   __attribute__((ext_vector_type(4)));
typedef int    int2v   __attribute__((ext_vector_type(2)));

static __device__ __forceinline__ short f2bf(float f) {
    unsigned u = __float_as_uint(f);
    unsigned r = (u + 0x7FFFu + ((u >> 16) & 1u)) >> 16;
    return (short)(r & 0xFFFFu);
}
static __device__ __forceinline__ int pack2(short a, short b) {
    return (int)((unsigned short)a | ((unsigned)(unsigned short)b << 16));
}
// async global->LDS, 16B per lane; LDS dest = wave-uniform base + lane*16
static __device__ __forceinline__ void async_cp16(const void* g, void* l) {
    __builtin_amdgcn_global_load_lds(
        (const __attribute__((address_space(1))) unsigned int*)g,
        (__attribute__((address_space(3))) unsigned int*)l, 16, 0, 0);
}

// ---------------------------------------------------------------------------
// prep: pre-swizzled bf16 weight streams, zero buffer, h2p halo zeroing.
// W1sw/W2sw: 4-chunk XOR swizzle c^((n>>1)&3) (conv12).
// W3sw: per-tap [tap][n][c][e] (n<288=ch*24+j), chunk c holds k-chunk c^(n&7).
// ---------------------------------------------------------------------------
__global__ __launch_bounds__(256) void prep_weights(
    const float* __restrict__ W1, const float* __restrict__ W2,
    const float* __restrict__ W3,
    short* __restrict__ W1sw, short* __restrict__ W2sw, short* __restrict__ W3sw,
    char* __restrict__ h2p, int4v* __restrict__ zerobuf)
{
    int tid = blockIdx.x * 256 + threadIdx.x;
    int stride = gridDim.x * 256;
    for (int i = tid; i < 5*256*8; i += stride) {
        int e = i & 7, q = (i >> 3) & 255, s = i >> 11;
        int n = q >> 2, c = q & 3;
        int gc = c ^ ((n >> 1) & 3);
        int tap = 2*s + (gc >> 1);
        int ch = (gc & 1)*8 + e;
        float v = 0.f;
        if (tap < 9) {
            int ky = (tap*11) >> 5; int kx = tap - 3*ky;
            v = W1[((n*16 + ch)*3 + ky)*3 + kx];
        }
        W1sw[i] = f2bf(v);
    }
    for (int i = tid; i < 2*256*8; i += stride) {
        int e = i & 7, q = (i >> 3) & 255, s = i >> 11;
        int n = q >> 2, c = q & 3;
        int gc = c ^ ((n >> 1) & 3);
        int k = s*32 + gc*8 + e;
        W2sw[i] = f2bf(W2[n*64 + k]);
    }
    // W3sw: 9 taps x 288 n x 8 chunks x 8 elems
    for (int i = tid; i < 9*288*64; i += stride) {
        int e = i & 7;
        int c = (i >> 3) & 7;
        int r = i >> 6;
        int tap = r / 288;
        int n = r - tap*288;
        int ch = n / 24, jj = n - 24*ch;
        int ci = ((c ^ (n & 7)) << 3) + e;
        float v = 0.f;
        if (jj < 23) v = W3[((ch*23 + jj)*64 + ci)*9 + tap];
        W3sw[i] = f2bf(v);
    }
    for (int i = tid; i < 64; i += stride) { int4v zz = {0,0,0,0}; zerobuf[i] = zz; }
    // h2p halo zero: 16 batches x 516 border px x 8 chunks
    for (int i = tid; i < 16*516*8; i += stride) {
        int cchunk = i & 7, pxi = (i >> 3) % 516, b = i / (516*8);
        int yy, xx;
        if (pxi < 130)      { yy = 0;   xx = pxi; }
        else if (pxi < 260) { yy = 129; xx = pxi - 130; }
        else if (pxi < 388) { yy = pxi - 260 + 1; xx = 0; }
        else                { yy = pxi - 388 + 1; xx = 129; }
        int4v zz = {0,0,0,0};
        *(int4v*)(h2p + (size_t)((b*130 + yy)*130 + xx)*128 + cchunk*16) = zz;
    }
}

// ---------------------------------------------------------------------------
// pack z with 1-px halo; zero logdet partial slots.
// ---------------------------------------------------------------------------
__global__ __launch_bounds__(256) void pack_z(
    const float* __restrict__ x, const float* __restrict__ cond,
    short* __restrict__ zp, float* __restrict__ ldslots)
{
    int id = blockIdx.x * 256 + threadIdx.x;
    if (id < 1024) ldslots[id] = 0.f;
    if (id >= 16*130*130) return;
    int b = id / 16900;
    int rem = id - b*16900;
    int yy = rem / 130;
    int xx = rem - yy*130;
    short vs[16];
    #pragma unroll
    for (int c = 0; c < 16; ++c) vs[c] = 0;
    if (yy >= 1 && yy <= 128 && xx >= 1 && xx <= 128) {
        int pix = (yy - 1)*128 + (xx - 1);
        bool frozen = ((yy + xx) & 1) == 1;
        #pragma unroll
        for (int c = 0; c < 12; ++c)
            vs[c] = f2bf(frozen ? x[(b*12 + c)*HW + pix] : 0.f);
        #pragma unroll
        for (int c = 0; c < 4; ++c)
            vs[12 + c] = f2bf(cond[(b*4 + c)*HW + pix]);
    }
    int4v lo = { pack2(vs[0],vs[1]),  pack2(vs[2],vs[3]),
                 pack2(vs[4],vs[5]),  pack2(vs[6],vs[7]) };
    int4v hi = { pack2(vs[8],vs[9]),  pack2(vs[10],vs[11]),
                 pack2(vs[12],vs[13]),pack2(vs[14],vs[15]) };
    *(int4v*)(zp + id*16)     = lo;
    *(int4v*)(zp + id*16 + 8) = hi;
}

// ---------------------------------------------------------------------------
// fused conv1 (3x3, 16->64) + conv2 (1x1, 64->64). Block = one image row.
// b = bid&15 pins batch to one XCD's L2.
// ---------------------------------------------------------------------------
__global__ __launch_bounds__(256, 4) void conv12_kernel(
    const char* __restrict__ zp, const char* __restrict__ W1sw,
    const char* __restrict__ W2sw,
    const float* __restrict__ b1, const float* __restrict__ b2,
    const char* __restrict__ zerobuf, char* __restrict__ h2p)
{
    __shared__ __align__(16) char smem[28672];
    int t = threadIdx.x;
    int lane = t & 63, w = t >> 6;
    int l15 = lane & 15, quad = lane >> 4;
    int bid = blockIdx.x;
    int b = bid & 15, y = bid >> 4;
    int chb = (w >> 1) * 32;
    int pxb = (w & 1) * 64;
    unsigned wbase = (unsigned)__builtin_amdgcn_readfirstlane(w << 10);

    int px1 = t >> 2;
    int gc1 = (t & 3) ^ ((px1 >> 1) & 3);
    int tl1 = gc1 >> 1, zoff1 = px1*32 + (gc1 & 1)*16;
    int q2 = t + 256;
    int px2 = q2 >> 2;
    int gc2 = (q2 & 3) ^ ((px2 >> 1) & 3);
    int tl2 = gc2 >> 1, zoff2 = px2*32 + (gc2 & 1)*16;

    int waddr[2], zaddr[4];
    #pragma unroll
    for (int i = 0; i < 2; ++i) {
        int n = chb + i*16 + l15;
        waddr[i] = 8192 + n*64 + ((quad ^ ((n >> 1) & 3)) << 4);
    }
    #pragma unroll
    for (int j = 0; j < 4; ++j) {
        int px = pxb + j*16 + l15;
        zaddr[j] = px*64 + ((quad ^ ((px >> 1) & 3)) << 4);
    }

    const char* zb = zp + (size_t)(b*16900)*32;
    const float4v z4 = {0.f,0.f,0.f,0.f};
    float4v acc[2][4];
    #pragma unroll
    for (int i = 0; i < 2; ++i)
        #pragma unroll
        for (int j = 0; j < 4; ++j) acc[i][j] = z4;

    for (int s = 0; s < 5; ++s) {
        __syncthreads();
        int ta = 2*s + tl1;
        const char* g1;
        if (ta < 9) { int ky = (ta*11) >> 5; int kx = ta - 3*ky;
            g1 = zb + ((y + ky)*130 + kx)*32 + zoff1; }
        else g1 = zerobuf + (lane << 4);
        async_cp16(g1, smem + wbase);
        int tb = 2*s + tl2;
        const char* g2;
        if (tb < 9) { int ky = (tb*11) >> 5; int kx = tb - 3*ky;
            g2 = zb + ((y + ky)*130 + kx)*32 + zoff2; }
        else g2 = zerobuf + (lane << 4);
        async_cp16(g2, smem + 4096 + wbase);
        async_cp16(W1sw + s*4096 + (t << 4), smem + 8192 + wbase);
        __syncthreads();
        bf16x8 aw[2];
        #pragma unroll
        for (int i = 0; i < 2; ++i) aw[i] = *(const bf16x8*)(smem + waddr[i]);
        #pragma unroll
        for (int j = 0; j < 4; ++j) {
            bf16x8 bzv = *(const bf16x8*)(smem + zaddr[j]);
            #pragma unroll
            for (int i = 0; i < 2; ++i)
                acc[i][j] = __builtin_amdgcn_mfma_f32_16x16x32_bf16(aw[i], bzv, acc[i][j], 0, 0, 0);
        }
    }
    {
        #pragma unroll
        for (int i = 0; i < 2; ++i) {
            int ch0 = chb + i*16 + quad*4;
            float bb0 = b1[ch0], bb1 = b1[ch0+1], bb2 = b1[ch0+2], bb3 = b1[ch0+3];
            #pragma unroll
            for (int j = 0; j < 4; ++j) {
                int px = pxb + j*16 + l15;
                short s0 = f2bf(fmaxf(acc[i][j][0] + bb0, 0.f));
                short s1 = f2bf(fmaxf(acc[i][j][1] + bb1, 0.f));
                short s2 = f2bf(fmaxf(acc[i][j][2] + bb2, 0.f));
                short s3 = f2bf(fmaxf(acc[i][j][3] + bb3, 0.f));
                int2v pk = { pack2(s0, s1), pack2(s2, s3) };
                *(int2v*)(smem + 12288 + px*128 + (((ch0 >> 3) ^ (px & 7)) << 4) + ((ch0 & 7) << 1)) = pk;
            }
        }
    }
    float4v acc2[2][4];
    #pragma unroll
    for (int i = 0; i < 2; ++i)
        #pragma unroll
        for (int j = 0; j < 4; ++j) acc2[i][j] = z4;
    for (int s = 0; s < 2; ++s) {
        __syncthreads();
        async_cp16(W2sw + s*4096 + (t << 4), smem + 8192 + wbase);
        __syncthreads();
        bf16x8 aw[2];
        #pragma unroll
        for (int i = 0; i < 2; ++i) aw[i] = *(const bf16x8*)(smem + waddr[i]);
        #pragma unroll
        for (int j = 0; j < 4; ++j) {
            int px = pxb + j*16 + l15;
            bf16x8 bh = *(const bf16x8*)(smem + 12288 + px*128 + (((s*4 + quad) ^ (px & 7)) << 4));
            #pragma unroll
            for (int i = 0; i < 2; ++i)
                acc2[i][j] = __builtin_amdgcn_mfma_f32_16x16x32_bf16(aw[i], bh, acc2[i][j], 0, 0, 0);
        }
    }
    __syncthreads();
    {
        #pragma unroll
        for (int i = 0; i < 2; ++i) {
            int ch0 = chb + i*16 + quad*4;
            float bb0 = b2[ch0], bb1 = b2[ch0+1], bb2 = b2[ch0+2], bb3 = b2[ch0+3];
            #pragma unroll
            for (int j = 0; j < 4; ++j) {
                int px = pxb + j*16 + l15;
                short s0 = f2bf(fmaxf(acc2[i][j][0] + bb0, 0.f));
                short s1 = f2bf(fmaxf(acc2[i][j][1] + bb1, 0.f));
                short s2 = f2bf(fmaxf(acc2[i][j][2] + bb2, 0.f));
                short s3 = f2bf(fmaxf(acc2[i][j][3] + bb3, 0.f));
                int2v pk = { pack2(s0, s1), pack2(s2, s3) };
                *(int2v*)(smem + 12288 + px*128 + (((ch0 >> 3) ^ (px & 7)) << 4) + ((ch0 & 7) << 1)) = pk;
            }
        }
    }
    __syncthreads();
    char* dst = h2p + ((size_t)(b*130 + y + 1)*130 + 1)*128;
    #pragma unroll
    for (int u = 0; u < 4; ++u) {
        int q = t + u*256;
        int px = q >> 3, g = q & 7;
        int4v v = *(const int4v*)(smem + 12288 + px*128 + ((g ^ (px & 7)) << 4));
        *(int4v*)(dst + px*128 + (g << 4)) = v;
    }
}

// ---------------------------------------------------------------------------
// RQS transform for one pixel given 23 params + x value. Returns y, adds lad.
// ---------------------------------------------------------------------------
static __device__ __forceinline__ float rqs_eval(
    const float* __restrict__ pa, float xin, bool frozen, float& ldsum)
{
    float xa = frozen ? 0.f : xin;
    float xf = frozen ? xin : 0.f;
    float xc = fminf(fmaxf(xa, -3.f), 3.f);
    bool inside = (xa >= -3.f) && (xa <= 3.f);

    float mw = pa[0];
    #pragma unroll
    for (int j = 1; j < 8; ++j) mw = fmaxf(mw, pa[j]);
    float ew[8]; float sw = 0.f;
    #pragma unroll
    for (int j = 0; j < 8; ++j) { ew[j] = __expf(pa[j] - mw); sw += ew[j]; }
    float Aw = 0.992f / sw;
    float run = 0.f, cwl = -3.f, icw = -3.f, iwid = 1.f;
    int idx = 0;
    #pragma unroll
    for (int j = 0; j < 8; ++j) {
        float wj = fmaf(Aw, ew[j], 0.001f);
        run += wj;
        float cwr = (j == 7) ? 3.f : fmaf(6.f, run, -3.f);
        if (xc >= cwl) { icw = cwl; iwid = cwr - cwl; idx = j; }
        cwl = cwr;
    }
    float mh = pa[8];
    #pragma unroll
    for (int j = 9; j < 16; ++j) mh = fmaxf(mh, pa[j]);
    float eh[8]; float sh = 0.f;
    #pragma unroll
    for (int j = 0; j < 8; ++j) { eh[j] = __expf(pa[8 + j] - mh); sh += eh[j]; }
    float Ah = 0.992f / sh;
    run = 0.f;
    float chl = -3.f, ich = 0.f, ihei = 1.f;
    #pragma unroll
    for (int j = 0; j < 8; ++j) {
        float hj = fmaf(Ah, eh[j], 0.001f);
        run += hj;
        float chr = (j == 7) ? 3.f : fmaf(6.f, run, -3.f);
        if (j == idx) { ich = chl; ihei = chr - chl; }
        chl = chr;
    }
    float v0 = 0.f, v1 = 0.f;
    bool h0 = false, h1 = false;
    #pragma unroll
    for (int j = 1; j < 8; ++j) {
        float v = pa[15 + j];
        if (j == idx)     { v0 = v; h0 = true; }
        if (j == idx + 1) { v1 = v; h1 = true; }
    }
    float sp0 = (v0 > 15.f) ? v0 : __logf(1.f + __expf(v0));
    float sp1 = (v1 > 15.f) ? v1 : __logf(1.f + __expf(v1));
    float d0 = h0 ? (0.001f + sp0) : 1.f;
    float d1 = h1 ? (0.001f + sp1) : 1.f;

    float dl = ihei / iwid;
    float th = (xc - icw) / iwid;
    float omt = 1.f - th;
    float t1 = th * omt;
    float num = ihei * (dl*th*th + d0*t1);
    float den = dl + (d0 + d1 - 2.f*dl)*t1;
    float yv = ich + num/den;
    float dnum = dl*dl*(d1*th*th + 2.f*dl*t1 + d0*omt*omt);
    float lad = __logf(dnum) - 2.f*__logf(den);

    ldsum += inside ? lad : 0.f;
    return xf + (inside ? yv : xa);
}

// ---------------------------------------------------------------------------
// conv3 (3x3, 64 -> 276 pad 288) fused with RQS.
// Block = 256 thr (4 waves), tile 128 px x 96 col; wave = 64 px x 48 col
// (acc[4][3] = 48 VGPR). Grid 6144 = 16b x 3cg x 128y, b = bid&15 XCD-pinned.
// 9 per-tap stages (k=64): A 16KB + B 12KB staged; reads/MFMA 0.58.
// ---------------------------------------------------------------------------
__global__ __launch_bounds__(256, 4) void conv3_rqs_kernel(
    const char* __restrict__ h2p, const char* __restrict__ W3sw,
    const float* __restrict__ b3, const float* __restrict__ x,
    float* __restrict__ out, float* __restrict__ ldslots)
{
    __shared__ __align__(16) char smem[28672];
    // staging: [0,16384) A-tile 128px x 128B | [16384,28672) B-tile 96n x 128B
    // epilogue (aliased): [0,26624) scr 64px x 104 floats
    int t = threadIdx.x;
    int lane = t & 63, w = t >> 6;
    int l15 = lane & 15, quad = lane >> 4;
    int bid = blockIdx.x;
    int b = bid & 15;
    int r0 = bid >> 4;
    int cg = r0 % 3;
    int y = r0 / 3;

    int u = w & 1, v = w >> 1;   // px-half (64), col-half (48)

    int aaddr[4], baddr[3];
    #pragma unroll
    for (int i = 0; i < 4; ++i) {
        int row = u*64 + i*16 + l15;
        aaddr[i] = row*128 + ((quad ^ (row & 7)) << 4);
    }
    #pragma unroll
    for (int j = 0; j < 3; ++j) {
        int nl = v*48 + j*16 + l15;
        baddr[j] = 16384 + nl*128 + ((quad ^ (nl & 7)) << 4);
    }

    // A staging offsets (4 rounds of 256 chunks)
    int offA[4];
    #pragma unroll
    for (int r = 0; r < 4; ++r) {
        int q = t + r*256;
        int px = q >> 3, c = q & 7;
        offA[r] = px*128 + ((c ^ (px & 7)) << 4);
    }
    unsigned wbase = (unsigned)__builtin_amdgcn_readfirstlane(w << 10);

    const float4v z4 = {0.f,0.f,0.f,0.f};
    float4v acc[4][3];
    #pragma unroll
    for (int i = 0; i < 4; ++i)
        #pragma unroll
        for (int j = 0; j < 3; ++j) acc[i][j] = z4;

    const char* h2pb = h2p + (size_t)(b*130)*130*128;
    const char* W3b = W3sw + cg*12288;
    for (int tap = 0; tap < 9; ++tap) {
        int ty = (tap*11) >> 5;
        int tx = tap - 3*ty;
        const char* sbA = h2pb + ((y + ty)*130 + tx)*128;
        const char* sbB = W3b + tap*36864;
        __syncthreads();
        #pragma unroll
        for (int r = 0; r < 4; ++r)
            async_cp16(sbA + offA[r], smem + r*4096 + wbase);
        #pragma unroll
        for (int r = 0; r < 3; ++r)
            async_cp16(sbB + r*4096 + (t << 4), smem + 16384 + r*4096 + wbase);
        __syncthreads();
        #pragma unroll
        for (int kh = 0; kh < 2; ++kh) {
            int kx = kh << 6;
            bf16x8 av[4];
            #pragma unroll
            for (int i = 0; i < 4; ++i)
                av[i] = *(const bf16x8*)(smem + (aaddr[i] ^ kx));
            #pragma unroll
            for (int j = 0; j < 3; ++j) {
                bf16x8 bv = *(const bf16x8*)(smem + (baddr[j] ^ kx));
                #pragma unroll
                for (int i = 0; i < 4; ++i)
                    acc[i][j] = __builtin_amdgcn_mfma_f32_16x16x32_bf16(av[i], bv, acc[i][j], 0, 0, 0);
            }
        }
    }
    __syncthreads();   // staging reads done -> reuse LDS as epilogue scratch

    // -------- epilogue: 2 rounds (px-half) x 1 task/thread, stride-104 scr ----
    float* scr = (float*)smem;   // [64 px][104]
    float ldsum = 0.f;
    int pxl = t & 63;
    int chl = t >> 6;            // 0..3
    int c = cg*4 + chl;
    const float* bb3 = b3 + c*23;

    #pragma unroll
    for (int rnd = 0; rnd < 2; ++rnd) {
        if (u == rnd) {
            #pragma unroll
            for (int i = 0; i < 4; ++i)
                #pragma unroll
                for (int j = 0; j < 3; ++j)
                    #pragma unroll
                    for (int r = 0; r < 4; ++r) {
                        int row = i*16 + quad*4 + r;
                        int col = v*48 + j*16 + l15;
                        scr[row*104 + col] = acc[i][j][r];
                    }
        }
        __syncthreads();
        const float* P = scr + pxl*104 + chl*24;
        float pa[23];
        {
            float pr[24];
            *(float4v*)&pr[0]  = *(const float4v*)(P);
            *(float4v*)&pr[4]  = *(const float4v*)(P + 4);
            *(float4v*)&pr[8]  = *(const float4v*)(P + 8);
            *(float4v*)&pr[12] = *(const float4v*)(P + 12);
            *(float4v*)&pr[16] = *(const float4v*)(P + 16);
            *(float4v*)&pr[20] = *(const float4v*)(P + 20);
            #pragma unroll
            for (int j = 0; j < 23; ++j) pa[j] = pr[j] + bb3[j];
        }
        int pxg = rnd*64 + pxl;
        int gidx = ((b*12 + c) << 14) + (y << 7) + pxg;
        float xin = x[gidx];
        bool frozen = ((y + pxg) & 1) == 1;
        out[gidx] = rqs_eval(pa, xin, frozen, ldsum);
        __syncthreads();
    }
    #pragma unroll
    for (int off = 32; off > 0; off >>= 1)
        ldsum += __shfl_down(ldsum, off, 64);
    if (lane == 0) atomicAdd(ldslots + b*64 + (r0 & 63), ldsum);
}

// ---------------------------------------------------------------------------
// final logdet reduce: 16 blocks x 64 lanes.
// ---------------------------------------------------------------------------
__global__ __launch_bounds__(64) void logdet_reduce(
    const float* __restrict__ ldslots, const float* __restrict__ ld_in,
    float* __restrict__ ldout)
{
    int b = blockIdx.x;
    int lane = threadIdx.x;
    float s = ldslots[b*64 + lane];
    #pragma unroll
    for (int off = 32; off > 0; off >>= 1)
        s += __shfl_down(s, off, 64);
    if (lane == 0) ldout[b] = ld_in[b] + s;
}

// ---------------------------------------------------------------------------
extern "C" void kernel_launch(void* const* d_in, const int* in_sizes, int n_in,
                              void* d_out, int out_size, void* d_ws, size_t ws_size,
                              hipStream_t stream)
{
    (void)in_sizes; (void)n_in; (void)out_size; (void)ws_size;
    const float* x    = (const float*)d_in[0];
    const float* ld   = (const float*)d_in[1];
    const float* cond = (const float*)d_in[2];
    const float* W1   = (const float*)d_in[3];
    const float* b1   = (const float*)d_in[4];
    const float* W2   = (const float*)d_in[5];
    const float* b2   = (const float*)d_in[6];
    const float* W3   = (const float*)d_in[7];
    const float* b3   = (const float*)d_in[8];
    float* out = (float*)d_out;
    char* ws = (char*)d_ws;

    short* zp     = (short*)(ws);              //  8,652,800 B
    char*  h2p    = ws + 8652800;              // 34,611,200 B
    short* W1sw   = (short*)(ws + 43264000);   //     20,480 B
    short* W2sw   = (short*)(ws + 43284480);   //      8,192 B
    short* W3sw   = (short*)(ws + 43292672);   //    331,776 B
    char*  zerob  = ws + 43624448;             //      1,024 B
    float* ldslots= (float*)(ws + 43625472);   //      4,096 B
    float* ldout  = out + 12*HW*16;

    prep_weights<<<dim3(256), dim3(256), 0, stream>>>(
        W1, W2, W3, W1sw, W2sw, W3sw, h2p, (int4v*)zerob);
    pack_z<<<dim3(1057), dim3(256), 0, stream>>>(x, cond, zp, ldslots);
    conv12_kernel<<<dim3(2048), dim3(256), 0, stream>>>(
        (const char*)zp, (const char*)W1sw, (const char*)W2sw, b1, b2,
        (const char*)zerob, h2p);
    conv3_rqs_kernel<<<dim3(6144), dim3(256), 0, stream>>>(
        (const char*)h2p, (const char*)W3sw, b3, x, out, ldslots);
    logdet_reduce<<<dim3(16), dim3(64), 0, stream>>>(ldslots, ld, ldout);
}